// Round 5
// baseline (396.868 us; speedup 1.0000x reference)
//
#include <hip/hip_runtime.h>
#include <math.h>

#define EPS 1e-5f

typedef short short8 __attribute__((ext_vector_type(8)));
typedef float f32x4 __attribute__((ext_vector_type(4)));
typedef unsigned short u16;
typedef u16 u16x4 __attribute__((ext_vector_type(4)));

__device__ inline u16 f2bf(float f) {
  union { float f; unsigned u; } x; x.f = f;
  return (u16)((x.u + 0x7fffu + ((x.u >> 16) & 1u)) >> 16);
}
__device__ inline float bf2f(u16 h) {
  union { float f; unsigned u; } x; x.u = ((unsigned)h) << 16;
  return x.f;
}

__device__ inline void gload_lds16(const void* g, void* l) {
  __builtin_amdgcn_global_load_lds((const __attribute__((address_space(1))) void*)g,
                                   (__attribute__((address_space(3))) void*)l, 16, 0, 0);
}

__global__ void k_zero(float* __restrict__ p, int n) {
  int i = blockIdx.x * 256 + threadIdx.x;
  if (i < n) p[i] = 0.f;
}

// ---------- BN1 column stats over X [N,512] + bf16 cast of X ----------
// Pure grid-stride float4 stream: flat over N*128 float4s. Column set per
// thread is constant (stride ≡ 0 mod 128), so LDS reduce by tid&127 works.
__global__ __launch_bounds__(256)
void k_bn1_statsX(const float* __restrict__ X, int N, float* __restrict__ s,
                  float* __restrict__ q, u16* __restrict__ Xb) {
  __shared__ float shs[1024], shq[1024];
  int tid = threadIdx.x;
  int c4 = tid & 127;  // float4-column index, constant across iterations
  float sum[4] = {0.f, 0.f, 0.f, 0.f}, sq[4] = {0.f, 0.f, 0.f, 0.f};
  size_t total = (size_t)N * 128;
  size_t stride = (size_t)gridDim.x * 256;
  for (size_t i = (size_t)blockIdx.x * 256 + tid; i < total; i += stride) {
    float4 v = ((const float4*)X)[i];
    u16x4 h;
    h[0] = f2bf(v.x); h[1] = f2bf(v.y); h[2] = f2bf(v.z); h[3] = f2bf(v.w);
    ((u16x4*)Xb)[i] = h;
    sum[0] += v.x; sq[0] += v.x * v.x;
    sum[1] += v.y; sq[1] += v.y * v.y;
    sum[2] += v.z; sq[2] += v.z * v.z;
    sum[3] += v.w; sq[3] += v.w * v.w;
  }
#pragma unroll
  for (int i = 0; i < 4; ++i) { shs[tid * 4 + i] = sum[i]; shq[tid * 4 + i] = sq[i]; }
  __syncthreads();
  if (tid < 128) {
#pragma unroll
    for (int i = 0; i < 4; ++i) {
      float a = shs[tid * 4 + i] + shs[(tid + 128) * 4 + i];
      float b = shq[tid * 4 + i] + shq[(tid + 128) * 4 + i];
      atomicAdd(&s[c4 * 4 + i], a);
      atomicAdd(&q[c4 * 4 + i], b);
    }
  }
}

// ---------- fold BN scale into TRANSPOSED bf16 weights: WT[j][k] = a[k]*W[k][j] ----------
__global__ void k_foldwT(const float* __restrict__ s, const float* __restrict__ q,
                         const float* __restrict__ gamma,
                         const float* __restrict__ W, u16* __restrict__ WT,
                         float invN, int lgK) {
  int idx = blockIdx.x * 256 + threadIdx.x;
  int K = 1 << lgK;
  int j = idx >> lgK, k = idx & (K - 1);
  float mu = s[k] * invN;
  float var = fmaxf(q[k] * invN - mu * mu, 0.f);
  float a = gamma[k] * rsqrtf(var + EPS);
  WT[idx] = f2bf(a * W[(size_t)k * 128 + j]);
}

// ---------- parallel fold BN shift: bp[j] += sum_k c[k]*W[k][j] (split-K, atomic) ----------
__global__ __launch_bounds__(256)
void k_foldb_par(const float* __restrict__ s, const float* __restrict__ q,
                 const float* __restrict__ gamma, const float* __restrict__ beta,
                 const float* __restrict__ W, const float* __restrict__ b,
                 float* __restrict__ bp, float invN, int kPerBlock) {
  __shared__ float sh[256];
  int j = threadIdx.x & 127;
  int ksub = threadIdx.x >> 7;  // 0..1
  int k0 = blockIdx.x * kPerBlock;
  float acc = 0.f;
  for (int k = k0 + ksub; k < k0 + kPerBlock; k += 2) {
    float mu = s[k] * invN;
    float var = fmaxf(q[k] * invN - mu * mu, 0.f);
    float a = gamma[k] * rsqrtf(var + EPS);
    float c = beta[k] - mu * a;
    acc = fmaf(c, W[(size_t)k * 128 + j], acc);
  }
  sh[threadIdx.x] = acc;
  __syncthreads();
  if (threadIdx.x < 128) {
    float v = sh[threadIdx.x] + sh[threadIdx.x + 128];
    if (blockIdx.x == 0) v += (b ? b[j] : 0.f);
    atomicAdd(&bp[j], v);
  }
}

// ---------- GEMM1 (MFMA bf16): Yb = relu(Xb@W1p + bp) as bf16; col stats of Y ----------
__global__ __launch_bounds__(256)
void k_gemm1(const u16* __restrict__ Xb, const u16* __restrict__ WT,
             const float* __restrict__ bp, u16* __restrict__ Yb,
             float* __restrict__ s2, float* __restrict__ q2, int N) {
  __shared__ __align__(16) u16 As[128 * 64];
  __shared__ __align__(16) u16 Bs[128 * 64];
  __shared__ float csum[128], cq[128];
  int tid = threadIdx.x;
  if (tid < 128) { csum[tid] = 0.f; cq[tid] = 0.f; }
  int lane = tid & 63, wid = tid >> 6;
  int wm = wid & 1, wn = wid >> 1;
  int bRow = blockIdx.x * 128;

  f32x4 acc[4][4];
#pragma unroll
  for (int mi = 0; mi < 4; ++mi)
#pragma unroll
    for (int ni = 0; ni < 4; ++ni) acc[mi][ni] = {0.f, 0.f, 0.f, 0.f};

  for (int k0 = 0; k0 < 512; k0 += 64) {
    __syncthreads();  // previous iteration's LDS readers done
#pragma unroll
    for (int i = 0; i < 4; ++i) {
      int p = i * 256 + tid;
      int row = p >> 3, slot = p & 7, srs = slot ^ (row & 7);
      int gr = bRow + row; if (gr >= N) gr = N - 1;
      gload_lds16(Xb + (size_t)gr * 512 + (k0 + srs * 8), (char*)As + p * 16);
      gload_lds16(WT + (size_t)row * 512 + (k0 + srs * 8), (char*)Bs + p * 16);
    }
    __syncthreads();  // drains vmcnt for gload_lds
#pragma unroll
    for (int ks = 0; ks < 2; ++ks) {
      short8 af[4], bfv[4];
#pragma unroll
      for (int mi = 0; mi < 4; ++mi) {
        int row = wm * 64 + mi * 16 + (lane & 15);
        int swz = (ks * 4 + (lane >> 4)) ^ (lane & 7);
        af[mi] = *(const short8*)(As + row * 64 + swz * 8);
      }
#pragma unroll
      for (int ni = 0; ni < 4; ++ni) {
        int row = wn * 64 + ni * 16 + (lane & 15);
        int swz = (ks * 4 + (lane >> 4)) ^ (lane & 7);
        bfv[ni] = *(const short8*)(Bs + row * 64 + swz * 8);
      }
#pragma unroll
      for (int mi = 0; mi < 4; ++mi)
#pragma unroll
        for (int ni = 0; ni < 4; ++ni)
          acc[mi][ni] = __builtin_amdgcn_mfma_f32_16x16x32_bf16(af[mi], bfv[ni], acc[mi][ni], 0, 0, 0);
    }
  }

  // epilogue: bias, relu, bf16 store, column stats
  float bias[4];
#pragma unroll
  for (int ni = 0; ni < 4; ++ni) bias[ni] = bp[wn * 64 + ni * 16 + (lane & 15)];
  float colp[4] = {0, 0, 0, 0}, colq[4] = {0, 0, 0, 0};
#pragma unroll
  for (int mi = 0; mi < 4; ++mi) {
#pragma unroll
    for (int r = 0; r < 4; ++r) {
      int gr = bRow + wm * 64 + mi * 16 + (lane >> 4) * 4 + r;
      if (gr < N) {
#pragma unroll
        for (int ni = 0; ni < 4; ++ni) {
          float u = fmaxf(acc[mi][ni][r] + bias[ni], 0.f);
          colp[ni] += u;
          colq[ni] += u * u;
          Yb[(size_t)gr * 128 + wn * 64 + ni * 16 + (lane & 15)] = f2bf(u);
        }
      }
    }
  }
#pragma unroll
  for (int ni = 0; ni < 4; ++ni) {
    float a = colp[ni], b = colq[ni];
    a += __shfl_xor(a, 16); a += __shfl_xor(a, 32);
    b += __shfl_xor(b, 16); b += __shfl_xor(b, 32);
    if (lane < 16) {
      atomicAdd(&csum[wn * 64 + ni * 16 + lane], a);
      atomicAdd(&cq[wn * 64 + ni * 16 + lane], b);
    }
  }
  __syncthreads();
  if (tid < 128) {
    atomicAdd(&s2[tid], csum[tid]);
    atomicAdd(&q2[tid], cq[tid]);
  }
}

// ---------- degree count ----------
__global__ void k_deg(const int* __restrict__ dst, int E, int* __restrict__ deg) {
  int e = blockIdx.x * 256 + threadIdx.x;
  if (e < E) atomicAdd(&deg[dst[e]], 1);
}

// ---------- scans ----------
__global__ __launch_bounds__(256)
void k_scan1(const int* __restrict__ deg, int N, int* __restrict__ offs,
             int* __restrict__ bsums, float* __restrict__ dinv) {
  __shared__ int sh[256];
  int t = threadIdx.x;
  int i = blockIdx.x * 256 + t;
  int c = (i < N) ? deg[i] : 0;
  if (i < N) dinv[i] = rsqrtf((float)(c + 1));
  int val = c;
  sh[t] = val;
  __syncthreads();
  for (int off = 1; off < 256; off <<= 1) {
    int add = (t >= off) ? sh[t - off] : 0;
    __syncthreads();
    val += add;
    sh[t] = val;
    __syncthreads();
  }
  if (i < N) offs[i] = val - c;
  if (t == 255) bsums[blockIdx.x] = val;
}

__global__ __launch_bounds__(256)
void k_scan2(int* __restrict__ bsums, int nb) {
  __shared__ int sh[256];
  int t = threadIdx.x;
  int v = (t < nb) ? bsums[t] : 0;
  int val = v;
  sh[t] = val;
  __syncthreads();
  for (int off = 1; off < 256; off <<= 1) {
    int add = (t >= off) ? sh[t - off] : 0;
    __syncthreads();
    val += add;
    sh[t] = val;
    __syncthreads();
  }
  if (t < nb) bsums[t] = val - v;
}

__global__ void k_scan3(int* __restrict__ offs, const int* __restrict__ bsums, int N) {
  int i = blockIdx.x * 256 + threadIdx.x;
  if (i < N) offs[i] += bsums[blockIdx.x];
}

// ---------- scatter src ids into CSR buckets ----------
__global__ void k_scatter(const int* __restrict__ src, const int* __restrict__ dst, int E,
                          const int* __restrict__ offs, int* __restrict__ cursor,
                          int* __restrict__ col) {
  int e = blockIdx.x * 256 + threadIdx.x;
  if (e < E) {
    int d = dst[e];
    int p = atomicAdd(&cursor[d], 1);
    col[offs[d] + p] = src[e];
  }
}

// ---------- gather (bf16 Y -> bf16 A): one wave per dst node, 4-way unrolled ----------
__global__ __launch_bounds__(256)
void k_gather(const u16* __restrict__ Yb, const int* __restrict__ col,
              const int* __restrict__ offs, const int* __restrict__ deg,
              const float* __restrict__ dinv, u16* __restrict__ Ab,
              float* __restrict__ scoef, int N) {
  int wid = threadIdx.x >> 6;
  int lane = threadIdx.x & 63;
  int d = blockIdx.x * 4 + wid;
  if (d >= N) return;
  int p = offs[d], c = deg[d];
  float dd = dinv[d];
  float ax, ay;
  {
    unsigned v = ((const unsigned*)(Yb + (size_t)d * 128))[lane];
    ax = dd * bf2f((u16)v);
    ay = dd * bf2f((u16)(v >> 16));
  }
  float sw = 0.f;
  for (int base = 0; base < c; base += 64) {
    int rem = c - base;
    if (rem > 64) rem = 64;
    int sidx = 0;
    float w = 0.f;
    if (lane < rem) {
      sidx = col[p + base + lane];
      w = dinv[sidx];
    }
    sw += w;
    int j = 0;
    for (; j + 3 < rem; j += 4) {
      int s0 = __shfl(sidx, j), s1 = __shfl(sidx, j + 1);
      int s2 = __shfl(sidx, j + 2), s3 = __shfl(sidx, j + 3);
      float w0 = __shfl(w, j), w1 = __shfl(w, j + 1);
      float w2 = __shfl(w, j + 2), w3 = __shfl(w, j + 3);
      unsigned v0 = ((const unsigned*)(Yb + (size_t)s0 * 128))[lane];
      unsigned v1 = ((const unsigned*)(Yb + (size_t)s1 * 128))[lane];
      unsigned v2 = ((const unsigned*)(Yb + (size_t)s2 * 128))[lane];
      unsigned v3 = ((const unsigned*)(Yb + (size_t)s3 * 128))[lane];
      ax = fmaf(w0, bf2f((u16)v0), ax); ay = fmaf(w0, bf2f((u16)(v0 >> 16)), ay);
      ax = fmaf(w1, bf2f((u16)v1), ax); ay = fmaf(w1, bf2f((u16)(v1 >> 16)), ay);
      ax = fmaf(w2, bf2f((u16)v2), ax); ay = fmaf(w2, bf2f((u16)(v2 >> 16)), ay);
      ax = fmaf(w3, bf2f((u16)v3), ax); ay = fmaf(w3, bf2f((u16)(v3 >> 16)), ay);
    }
    for (; j < rem; ++j) {
      int sj = __shfl(sidx, j);
      float wj = __shfl(w, j);
      unsigned v = ((const unsigned*)(Yb + (size_t)sj * 128))[lane];
      ax = fmaf(wj, bf2f((u16)v), ax);
      ay = fmaf(wj, bf2f((u16)(v >> 16)), ay);
    }
  }
#pragma unroll
  for (int off = 32; off; off >>= 1) sw += __shfl_xor(sw, off);
  unsigned o = (unsigned)f2bf(ax * dd) | ((unsigned)f2bf(ay * dd) << 16);
  ((unsigned*)(Ab + (size_t)d * 128))[lane] = o;
  if (lane == 0) scoef[d] = dd * (sw + dd);
}

// ---------- final (MFMA bf16, BK=128 single pass) ----------
__global__ __launch_bounds__(256)
void k_final(const u16* __restrict__ Ab, const u16* __restrict__ W2T,
             const float* __restrict__ hc, const float* __restrict__ scoef,
             const float* __restrict__ bg, const float* __restrict__ Wcls,
             const float* __restrict__ bcls, float* __restrict__ out, int N) {
  __shared__ __align__(16) char smem[65536];
  __shared__ float WcS[1280];
  __shared__ float hcS[128], bgS[128], bcS[10];
  u16* As = (u16*)smem;            // [128 rows][128 k] swizzled, 32KB
  u16* Bs = (u16*)(smem + 32768);  // [128 cols][128 k] swizzled, 32KB
  u16* Tb = (u16*)smem;            // reused after compute: [128][136] bf16
  int tid = threadIdx.x;
  for (int i = tid; i < 1280; i += 256) WcS[i] = Wcls[i];
  if (tid < 128) { hcS[tid] = hc[tid]; bgS[tid] = bg[tid]; }
  if (tid < 10) bcS[tid] = bcls[tid];
  int lane = tid & 63, wid = tid >> 6;
  int wm = wid & 1, wn = wid >> 1;
  int bRow = blockIdx.x * 128;

  // stage A and B tiles (whole K=128)
#pragma unroll
  for (int i = 0; i < 8; ++i) {
    int p = i * 256 + tid;
    int row = p >> 4, slot = p & 15, srs = slot ^ (row & 7);
    int gr = bRow + row; if (gr >= N) gr = N - 1;
    gload_lds16(Ab + (size_t)gr * 128 + srs * 8, (char*)As + p * 16);
    gload_lds16(W2T + (size_t)row * 128 + srs * 8, (char*)Bs + p * 16);
  }
  f32x4 acc[4][4];
#pragma unroll
  for (int mi = 0; mi < 4; ++mi)
#pragma unroll
    for (int ni = 0; ni < 4; ++ni) acc[mi][ni] = {0.f, 0.f, 0.f, 0.f};
  __syncthreads();
#pragma unroll
  for (int ks = 0; ks < 4; ++ks) {
    short8 af[4], bfv[4];
#pragma unroll
    for (int mi = 0; mi < 4; ++mi) {
      int row = wm * 64 + mi * 16 + (lane & 15);
      int swz = (ks * 4 + (lane >> 4)) ^ (lane & 7);
      af[mi] = *(const short8*)(As + row * 128 + swz * 8);
    }
#pragma unroll
    for (int ni = 0; ni < 4; ++ni) {
      int row = wn * 64 + ni * 16 + (lane & 15);
      int swz = (ks * 4 + (lane >> 4)) ^ (lane & 7);
      bfv[ni] = *(const short8*)(Bs + row * 128 + swz * 8);
    }
#pragma unroll
    for (int mi = 0; mi < 4; ++mi)
#pragma unroll
      for (int ni = 0; ni < 4; ++ni)
        acc[mi][ni] = __builtin_amdgcn_mfma_f32_16x16x32_bf16(af[mi], bfv[ni], acc[mi][ni], 0, 0, 0);
  }
  __syncthreads();  // all LDS reads done before Tb overwrite

  // epilogue: u = acc + hc*scoef + bg, relu -> Tb (bf16)
  float hcv[4], bgv[4];
#pragma unroll
  for (int ni = 0; ni < 4; ++ni) {
    int n = wn * 64 + ni * 16 + (lane & 15);
    hcv[ni] = hcS[n];
    bgv[ni] = bgS[n];
  }
#pragma unroll
  for (int mi = 0; mi < 4; ++mi) {
#pragma unroll
    for (int r = 0; r < 4; ++r) {
      int m = wm * 64 + mi * 16 + (lane >> 4) * 4 + r;
      int gr = bRow + m;
      float sc = (gr < N) ? scoef[gr] : 0.f;
#pragma unroll
      for (int ni = 0; ni < 4; ++ni) {
        float u = fmaxf(acc[mi][ni][r] + hcv[ni] * sc + bgv[ni], 0.f);
        Tb[m * 136 + wn * 64 + ni * 16 + (lane & 15)] = f2bf(u);
      }
    }
  }
  __syncthreads();

  // classifier + log_softmax: 2 threads per row
  int r2 = tid >> 1, qd = tid & 1;
  float part[10];
#pragma unroll
  for (int t = 0; t < 10; ++t) part[t] = 0.f;
  for (int jj = 0; jj < 64; ++jj) {
    int j = qd * 64 + jj;
    float a = bf2f(Tb[r2 * 136 + j]);
#pragma unroll
    for (int t = 0; t < 10; ++t) part[t] = fmaf(a, WcS[j * 10 + t], part[t]);
  }
#pragma unroll
  for (int t = 0; t < 10; ++t) part[t] += __shfl_xor(part[t], 1);
  int gr = bRow + r2;
  if (qd == 0 && gr < N) {
    float l[10], m = -1e30f;
#pragma unroll
    for (int t = 0; t < 10; ++t) {
      l[t] = part[t] + bcS[t];
      m = fmaxf(m, l[t]);
    }
    float se = 0.f;
#pragma unroll
    for (int t = 0; t < 10; ++t) se += expf(l[t] - m);
    float lse = m + logf(se);
#pragma unroll
    for (int t = 0; t < 10; ++t) out[(size_t)gr * 10 + t] = l[t] - lse;
  }
}

// ---------------------------------------------------------------------------
extern "C" void kernel_launch(void* const* d_in, const int* in_sizes, int n_in,
                              void* d_out, int out_size, void* d_ws, size_t ws_size,
                              hipStream_t stream) {
  const float* X = (const float*)d_in[0];
  const int* ei = (const int*)d_in[2];
  const float* gamma1 = (const float*)d_in[3];
  const float* beta1 = (const float*)d_in[4];
  const float* Wmlp = (const float*)d_in[5];
  const float* bmlp = (const float*)d_in[6];
  const float* gamma2 = (const float*)d_in[7];
  const float* beta2 = (const float*)d_in[8];
  const float* Wgcn = (const float*)d_in[9];
  const float* bgcn = (const float*)d_in[10];
  const float* Wcls = (const float*)d_in[11];
  const float* bcls = (const float*)d_in[12];
  float* out = (float*)d_out;

  const int N = in_sizes[0] / 512;
  const int E = in_sizes[2] / 2;
  const float invN = 1.0f / (float)N;

  char* ws = (char*)d_ws;
  float* s1 = (float*)(ws + 0);            // 512
  float* q1 = (float*)(ws + 2048);         // 512
  float* s2 = (float*)(ws + 4096);         // 128
  float* q2 = (float*)(ws + 4608);         // 128
  float* b1p = (float*)(ws + 5120);        // 128
  float* hconst = (float*)(ws + 5632);     // 128
  u16* W1bT = (u16*)(ws + 8192);           // 128*512 bf16 -> ends 139264
  u16* W2bT = (u16*)(ws + 139264);         // 128*128 bf16 -> ends 172032
  int* bsums = (int*)(ws + 172032);        // 256 -> 173056
  int* deg = (int*)(ws + 173056);          // N
  int* cursor = (int*)(ws + 373056);       // N
  int* offs = (int*)(ws + 573056);         // N
  float* dinv = (float*)(ws + 773056);     // N
  float* scoef = (float*)(ws + 973056);    // N
  int* col = (int*)(ws + 1173056);         // E -> 4373056
  u16* Yb = (u16*)(ws + 4373504);          // N*128 bf16 -> 17173504
  u16* Ab = (u16*)(ws + 17173504);         // N*128 bf16 -> 29973504
  u16* Xb = (u16*)(ws + 29973504);         // N*512 bf16 -> 81173504
  (void)ws_size; (void)n_in; (void)out_size;

  const int* esrc = ei;
  const int* edst = ei + E;
  int nb = (N + 255) / 256;
  int eb = (E + 255) / 256;
  int gb = (N + 127) / 128;  // 391

  // zero stats + b1p + hconst (contiguous 1536 floats at ws+0)
  k_zero<<<6, 256, 0, stream>>>(s1, 1536);
  k_zero<<<(2 * N + 255) / 256, 256, 0, stream>>>((float*)deg, 2 * N);

  k_bn1_statsX<<<2048, 256, 0, stream>>>(X, N, s1, q1, Xb);
  k_foldwT<<<256, 256, 0, stream>>>(s1, q1, gamma1, Wmlp, W1bT, invN, 9);
  k_foldb_par<<<16, 256, 0, stream>>>(s1, q1, gamma1, beta1, Wmlp, bmlp, b1p, invN, 32);
  k_gemm1<<<gb, 256, 0, stream>>>(Xb, W1bT, b1p, Yb, s2, q2, N);

  k_deg<<<eb, 256, 0, stream>>>(edst, E, deg);
  k_scan1<<<nb, 256, 0, stream>>>(deg, N, offs, bsums, dinv);
  k_scan2<<<1, 256, 0, stream>>>(bsums, nb);
  k_scan3<<<nb, 256, 0, stream>>>(offs, bsums, N);
  k_scatter<<<eb, 256, 0, stream>>>(esrc, edst, E, offs, cursor, col);

  k_foldwT<<<64, 256, 0, stream>>>(s2, q2, gamma2, Wgcn, W2bT, invN, 7);
  k_foldb_par<<<8, 256, 0, stream>>>(s2, q2, gamma2, beta2, Wgcn, nullptr, hconst, invN, 16);

  k_gather<<<(N + 3) / 4, 256, 0, stream>>>(Yb, col, offs, deg, dinv, Ab, scoef, N);
  k_final<<<gb, 256, 0, stream>>>(Ab, W2bT, hconst, scoef, bgcn, Wcls, bcls, out, N);
}

// Round 6
// 249.597 us; speedup vs baseline: 1.5900x; 1.5900x over previous
//
#include <hip/hip_runtime.h>
#include <math.h>

#define EPS 1e-5f

typedef short short8 __attribute__((ext_vector_type(8)));
typedef float f32x4 __attribute__((ext_vector_type(4)));
typedef unsigned short u16;
typedef u16 u16x4 __attribute__((ext_vector_type(4)));

__device__ inline u16 f2bf(float f) {
  union { float f; unsigned u; } x; x.f = f;
  return (u16)((x.u + 0x7fffu + ((x.u >> 16) & 1u)) >> 16);
}
__device__ inline float bf2f(u16 h) {
  union { float f; unsigned u; } x; x.u = ((unsigned)h) << 16;
  return x.f;
}

__device__ inline void gload_lds16(const void* g, void* l) {
  __builtin_amdgcn_global_load_lds((const __attribute__((address_space(1))) void*)g,
                                   (__attribute__((address_space(3))) void*)l, 16, 0, 0);
}

__global__ void k_zero(float* __restrict__ p, int n) {
  int i = blockIdx.x * 256 + threadIdx.x;
  if (i < n) p[i] = 0.f;
}

// ---------- BN1 column stats over X [N,512] + bf16 cast of X ----------
// Grid-stride float4 stream; per-block partials -> pS/pQ (NO global atomics:
// same-address atomicAdd costs ~115ns per block serially -- measured r3-r5).
__global__ __launch_bounds__(256)
void k_bn1_statsX(const float* __restrict__ X, int N, float* __restrict__ pS,
                  float* __restrict__ pQ, u16* __restrict__ Xb) {
  __shared__ float shs[1024], shq[1024];
  int tid = threadIdx.x;
  float sum[4] = {0.f, 0.f, 0.f, 0.f}, sq[4] = {0.f, 0.f, 0.f, 0.f};
  size_t total = (size_t)N * 128;
  size_t stride = (size_t)gridDim.x * 256;
  for (size_t i = (size_t)blockIdx.x * 256 + tid; i < total; i += stride) {
    float4 v = ((const float4*)X)[i];
    u16x4 h;
    h[0] = f2bf(v.x); h[1] = f2bf(v.y); h[2] = f2bf(v.z); h[3] = f2bf(v.w);
    ((u16x4*)Xb)[i] = h;
    sum[0] += v.x; sq[0] += v.x * v.x;
    sum[1] += v.y; sq[1] += v.y * v.y;
    sum[2] += v.z; sq[2] += v.z * v.z;
    sum[3] += v.w; sq[3] += v.w * v.w;
  }
#pragma unroll
  for (int i = 0; i < 4; ++i) { shs[tid * 4 + i] = sum[i]; shq[tid * 4 + i] = sq[i]; }
  __syncthreads();
  // columns: thread tid covers cols (tid&127)*4 .. +3 (grid stride ≡ 0 mod 128)
  if (tid < 128) {
#pragma unroll
    for (int i = 0; i < 4; ++i) {
      float a = shs[tid * 4 + i] + shs[(tid + 128) * 4 + i];
      float b = shq[tid * 4 + i] + shq[(tid + 128) * 4 + i];
      pS[(size_t)blockIdx.x * 512 + tid * 4 + i] = a;
      pQ[(size_t)blockIdx.x * 512 + tid * 4 + i] = b;
    }
  }
}

// ---------- reduce stage-1 partials: s[col] = sum_p pS[p][col], 512 cols ----------
__global__ __launch_bounds__(256)
void k_red1(const float* __restrict__ pS, const float* __restrict__ pQ,
            float* __restrict__ s, float* __restrict__ q, int P, int per) {
  int t = threadIdx.x;
  int p0 = blockIdx.x * per;
  int p1 = p0 + per; if (p1 > P) p1 = P;
  float a0 = 0.f, a1 = 0.f, b0 = 0.f, b1 = 0.f;
  for (int p = p0; p < p1; ++p) {
    a0 += pS[(size_t)p * 512 + t];
    a1 += pS[(size_t)p * 512 + t + 256];
    b0 += pQ[(size_t)p * 512 + t];
    b1 += pQ[(size_t)p * 512 + t + 256];
  }
  atomicAdd(&s[t], a0); atomicAdd(&s[t + 256], a1);
  atomicAdd(&q[t], b0); atomicAdd(&q[t + 256], b1);
}

// ---------- reduce gemm1 partials: 128 cols ----------
__global__ __launch_bounds__(256)
void k_red2(const float* __restrict__ pS, const float* __restrict__ pQ,
            float* __restrict__ s, float* __restrict__ q, int NB, int per) {
  int t = threadIdx.x;
  int col = t & 127;
  const float* src = (t >= 128) ? pQ : pS;
  int p0 = blockIdx.x * per;
  int p1 = p0 + per; if (p1 > NB) p1 = NB;
  float a = 0.f;
  for (int p = p0; p < p1; ++p) a += src[(size_t)p * 128 + col];
  atomicAdd((t >= 128) ? &q[col] : &s[col], a);
}

// ---------- fold BN scale into TRANSPOSED bf16 weights: WT[j][k] = a[k]*W[k][j] ----------
__global__ void k_foldwT(const float* __restrict__ s, const float* __restrict__ q,
                         const float* __restrict__ gamma,
                         const float* __restrict__ W, u16* __restrict__ WT,
                         float invN, int lgK) {
  int idx = blockIdx.x * 256 + threadIdx.x;
  int K = 1 << lgK;
  int j = idx >> lgK, k = idx & (K - 1);
  float mu = s[k] * invN;
  float var = fmaxf(q[k] * invN - mu * mu, 0.f);
  float a = gamma[k] * rsqrtf(var + EPS);
  WT[idx] = f2bf(a * W[(size_t)k * 128 + j]);
}

// ---------- parallel fold BN shift: bp[j] += sum_k c[k]*W[k][j] (split-K, atomic) ----------
__global__ __launch_bounds__(256)
void k_foldb_par(const float* __restrict__ s, const float* __restrict__ q,
                 const float* __restrict__ gamma, const float* __restrict__ beta,
                 const float* __restrict__ W, const float* __restrict__ b,
                 float* __restrict__ bp, float invN, int kPerBlock) {
  __shared__ float sh[256];
  int j = threadIdx.x & 127;
  int ksub = threadIdx.x >> 7;  // 0..1
  int k0 = blockIdx.x * kPerBlock;
  float acc = 0.f;
  for (int k = k0 + ksub; k < k0 + kPerBlock; k += 2) {
    float mu = s[k] * invN;
    float var = fmaxf(q[k] * invN - mu * mu, 0.f);
    float a = gamma[k] * rsqrtf(var + EPS);
    float c = beta[k] - mu * a;
    acc = fmaf(c, W[(size_t)k * 128 + j], acc);
  }
  sh[threadIdx.x] = acc;
  __syncthreads();
  if (threadIdx.x < 128) {
    float v = sh[threadIdx.x] + sh[threadIdx.x + 128];
    if (blockIdx.x == 0) v += (b ? b[j] : 0.f);
    atomicAdd(&bp[j], v);
  }
}

// ---------- GEMM1 (MFMA bf16): Yb = relu(Xb@W1p + bp) as bf16; partial col stats ----------
__global__ __launch_bounds__(256)
void k_gemm1(const u16* __restrict__ Xb, const u16* __restrict__ WT,
             const float* __restrict__ bp, u16* __restrict__ Yb,
             float* __restrict__ pS2, float* __restrict__ pQ2, int N) {
  __shared__ __align__(16) u16 As[128 * 64];
  __shared__ __align__(16) u16 Bs[128 * 64];
  __shared__ float csum[128], cq[128];
  int tid = threadIdx.x;
  if (tid < 128) { csum[tid] = 0.f; cq[tid] = 0.f; }
  int lane = tid & 63, wid = tid >> 6;
  int wm = wid & 1, wn = wid >> 1;
  int bRow = blockIdx.x * 128;

  f32x4 acc[4][4];
#pragma unroll
  for (int mi = 0; mi < 4; ++mi)
#pragma unroll
    for (int ni = 0; ni < 4; ++ni) acc[mi][ni] = {0.f, 0.f, 0.f, 0.f};

  for (int k0 = 0; k0 < 512; k0 += 64) {
    __syncthreads();  // previous iteration's LDS readers done
#pragma unroll
    for (int i = 0; i < 4; ++i) {
      int p = i * 256 + tid;
      int row = p >> 3, slot = p & 7, srs = slot ^ (row & 7);
      int gr = bRow + row; if (gr >= N) gr = N - 1;
      gload_lds16(Xb + (size_t)gr * 512 + (k0 + srs * 8), (char*)As + p * 16);
      gload_lds16(WT + (size_t)row * 512 + (k0 + srs * 8), (char*)Bs + p * 16);
    }
    __syncthreads();  // drains vmcnt for gload_lds
#pragma unroll
    for (int ks = 0; ks < 2; ++ks) {
      short8 af[4], bfv[4];
#pragma unroll
      for (int mi = 0; mi < 4; ++mi) {
        int row = wm * 64 + mi * 16 + (lane & 15);
        int swz = (ks * 4 + (lane >> 4)) ^ (lane & 7);
        af[mi] = *(const short8*)(As + row * 64 + swz * 8);
      }
#pragma unroll
      for (int ni = 0; ni < 4; ++ni) {
        int row = wn * 64 + ni * 16 + (lane & 15);
        int swz = (ks * 4 + (lane >> 4)) ^ (lane & 7);
        bfv[ni] = *(const short8*)(Bs + row * 64 + swz * 8);
      }
#pragma unroll
      for (int mi = 0; mi < 4; ++mi)
#pragma unroll
        for (int ni = 0; ni < 4; ++ni)
          acc[mi][ni] = __builtin_amdgcn_mfma_f32_16x16x32_bf16(af[mi], bfv[ni], acc[mi][ni], 0, 0, 0);
    }
  }

  // epilogue: bias, relu, bf16 store, column stats
  float bias[4];
#pragma unroll
  for (int ni = 0; ni < 4; ++ni) bias[ni] = bp[wn * 64 + ni * 16 + (lane & 15)];
  float colp[4] = {0, 0, 0, 0}, colq[4] = {0, 0, 0, 0};
#pragma unroll
  for (int mi = 0; mi < 4; ++mi) {
#pragma unroll
    for (int r = 0; r < 4; ++r) {
      int gr = bRow + wm * 64 + mi * 16 + (lane >> 4) * 4 + r;
      if (gr < N) {
#pragma unroll
        for (int ni = 0; ni < 4; ++ni) {
          float u = fmaxf(acc[mi][ni][r] + bias[ni], 0.f);
          colp[ni] += u;
          colq[ni] += u * u;
          Yb[(size_t)gr * 128 + wn * 64 + ni * 16 + (lane & 15)] = f2bf(u);
        }
      }
    }
  }
#pragma unroll
  for (int ni = 0; ni < 4; ++ni) {
    float a = colp[ni], b = colq[ni];
    a += __shfl_xor(a, 16); a += __shfl_xor(a, 32);
    b += __shfl_xor(b, 16); b += __shfl_xor(b, 32);
    if (lane < 16) {
      atomicAdd(&csum[wn * 64 + ni * 16 + lane], a);
      atomicAdd(&cq[wn * 64 + ni * 16 + lane], b);
    }
  }
  __syncthreads();
  if (tid < 128) {
    pS2[(size_t)blockIdx.x * 128 + tid] = csum[tid];
    pQ2[(size_t)blockIdx.x * 128 + tid] = cq[tid];
  }
}

// ---------- degree count ----------
__global__ void k_deg(const int* __restrict__ dst, int E, int* __restrict__ deg) {
  int e = blockIdx.x * 256 + threadIdx.x;
  if (e < E) atomicAdd(&deg[dst[e]], 1);
}

// ---------- scans ----------
__global__ __launch_bounds__(256)
void k_scan1(const int* __restrict__ deg, int N, int* __restrict__ offs,
             int* __restrict__ bsums, float* __restrict__ dinv) {
  __shared__ int sh[256];
  int t = threadIdx.x;
  int i = blockIdx.x * 256 + t;
  int c = (i < N) ? deg[i] : 0;
  if (i < N) dinv[i] = rsqrtf((float)(c + 1));
  int val = c;
  sh[t] = val;
  __syncthreads();
  for (int off = 1; off < 256; off <<= 1) {
    int add = (t >= off) ? sh[t - off] : 0;
    __syncthreads();
    val += add;
    sh[t] = val;
    __syncthreads();
  }
  if (i < N) offs[i] = val - c;
  if (t == 255) bsums[blockIdx.x] = val;
}

__global__ __launch_bounds__(256)
void k_scan2(int* __restrict__ bsums, int nb) {
  __shared__ int sh[256];
  int t = threadIdx.x;
  int v = (t < nb) ? bsums[t] : 0;
  int val = v;
  sh[t] = val;
  __syncthreads();
  for (int off = 1; off < 256; off <<= 1) {
    int add = (t >= off) ? sh[t - off] : 0;
    __syncthreads();
    val += add;
    sh[t] = val;
    __syncthreads();
  }
  if (t < nb) bsums[t] = val - v;
}

__global__ void k_scan3(int* __restrict__ offs, const int* __restrict__ bsums, int N) {
  int i = blockIdx.x * 256 + threadIdx.x;
  if (i < N) offs[i] += bsums[blockIdx.x];
}

// ---------- scatter src ids into CSR buckets ----------
__global__ void k_scatter(const int* __restrict__ src, const int* __restrict__ dst, int E,
                          const int* __restrict__ offs, int* __restrict__ cursor,
                          int* __restrict__ col) {
  int e = blockIdx.x * 256 + threadIdx.x;
  if (e < E) {
    int d = dst[e];
    int p = atomicAdd(&cursor[d], 1);
    col[offs[d] + p] = src[e];
  }
}

// ---------- gather (bf16 Y -> bf16 A): one wave per dst node, 4-way unrolled ----------
__global__ __launch_bounds__(256)
void k_gather(const u16* __restrict__ Yb, const int* __restrict__ col,
              const int* __restrict__ offs, const int* __restrict__ deg,
              const float* __restrict__ dinv, u16* __restrict__ Ab,
              float* __restrict__ scoef, int N) {
  int wid = threadIdx.x >> 6;
  int lane = threadIdx.x & 63;
  int d = blockIdx.x * 4 + wid;
  if (d >= N) return;
  int p = offs[d], c = deg[d];
  float dd = dinv[d];
  float ax, ay;
  {
    unsigned v = ((const unsigned*)(Yb + (size_t)d * 128))[lane];
    ax = dd * bf2f((u16)v);
    ay = dd * bf2f((u16)(v >> 16));
  }
  float sw = 0.f;
  for (int base = 0; base < c; base += 64) {
    int rem = c - base;
    if (rem > 64) rem = 64;
    int sidx = 0;
    float w = 0.f;
    if (lane < rem) {
      sidx = col[p + base + lane];
      w = dinv[sidx];
    }
    sw += w;
    int j = 0;
    for (; j + 3 < rem; j += 4) {
      int s0 = __shfl(sidx, j), s1 = __shfl(sidx, j + 1);
      int s2 = __shfl(sidx, j + 2), s3 = __shfl(sidx, j + 3);
      float w0 = __shfl(w, j), w1 = __shfl(w, j + 1);
      float w2 = __shfl(w, j + 2), w3 = __shfl(w, j + 3);
      unsigned v0 = ((const unsigned*)(Yb + (size_t)s0 * 128))[lane];
      unsigned v1 = ((const unsigned*)(Yb + (size_t)s1 * 128))[lane];
      unsigned v2 = ((const unsigned*)(Yb + (size_t)s2 * 128))[lane];
      unsigned v3 = ((const unsigned*)(Yb + (size_t)s3 * 128))[lane];
      ax = fmaf(w0, bf2f((u16)v0), ax); ay = fmaf(w0, bf2f((u16)(v0 >> 16)), ay);
      ax = fmaf(w1, bf2f((u16)v1), ax); ay = fmaf(w1, bf2f((u16)(v1 >> 16)), ay);
      ax = fmaf(w2, bf2f((u16)v2), ax); ay = fmaf(w2, bf2f((u16)(v2 >> 16)), ay);
      ax = fmaf(w3, bf2f((u16)v3), ax); ay = fmaf(w3, bf2f((u16)(v3 >> 16)), ay);
    }
    for (; j < rem; ++j) {
      int sj = __shfl(sidx, j);
      float wj = __shfl(w, j);
      unsigned v = ((const unsigned*)(Yb + (size_t)sj * 128))[lane];
      ax = fmaf(wj, bf2f((u16)v), ax);
      ay = fmaf(wj, bf2f((u16)(v >> 16)), ay);
    }
  }
#pragma unroll
  for (int off = 32; off; off >>= 1) sw += __shfl_xor(sw, off);
  unsigned o = (unsigned)f2bf(ax * dd) | ((unsigned)f2bf(ay * dd) << 16);
  ((unsigned*)(Ab + (size_t)d * 128))[lane] = o;
  if (lane == 0) scoef[d] = dd * (sw + dd);
}

// ---------- final (MFMA bf16, BK=128 single pass) ----------
__global__ __launch_bounds__(256)
void k_final(const u16* __restrict__ Ab, const u16* __restrict__ W2T,
             const float* __restrict__ hc, const float* __restrict__ scoef,
             const float* __restrict__ bg, const float* __restrict__ Wcls,
             const float* __restrict__ bcls, float* __restrict__ out, int N) {
  __shared__ __align__(16) char smem[65536];
  __shared__ float WcS[1280];
  __shared__ float hcS[128], bgS[128], bcS[10];
  u16* As = (u16*)smem;            // [128 rows][128 k] swizzled, 32KB
  u16* Bs = (u16*)(smem + 32768);  // [128 cols][128 k] swizzled, 32KB
  u16* Tb = (u16*)smem;            // reused after compute: [128][136] bf16
  int tid = threadIdx.x;
  for (int i = tid; i < 1280; i += 256) WcS[i] = Wcls[i];
  if (tid < 128) { hcS[tid] = hc[tid]; bgS[tid] = bg[tid]; }
  if (tid < 10) bcS[tid] = bcls[tid];
  int lane = tid & 63, wid = tid >> 6;
  int wm = wid & 1, wn = wid >> 1;
  int bRow = blockIdx.x * 128;

  // stage A and B tiles (whole K=128)
#pragma unroll
  for (int i = 0; i < 8; ++i) {
    int p = i * 256 + tid;
    int row = p >> 4, slot = p & 15, srs = slot ^ (row & 7);
    int gr = bRow + row; if (gr >= N) gr = N - 1;
    gload_lds16(Ab + (size_t)gr * 128 + srs * 8, (char*)As + p * 16);
    gload_lds16(W2T + (size_t)row * 128 + srs * 8, (char*)Bs + p * 16);
  }
  f32x4 acc[4][4];
#pragma unroll
  for (int mi = 0; mi < 4; ++mi)
#pragma unroll
    for (int ni = 0; ni < 4; ++ni) acc[mi][ni] = {0.f, 0.f, 0.f, 0.f};
  __syncthreads();
#pragma unroll
  for (int ks = 0; ks < 4; ++ks) {
    short8 af[4], bfv[4];
#pragma unroll
    for (int mi = 0; mi < 4; ++mi) {
      int row = wm * 64 + mi * 16 + (lane & 15);
      int swz = (ks * 4 + (lane >> 4)) ^ (lane & 7);
      af[mi] = *(const short8*)(As + row * 128 + swz * 8);
    }
#pragma unroll
    for (int ni = 0; ni < 4; ++ni) {
      int row = wn * 64 + ni * 16 + (lane & 15);
      int swz = (ks * 4 + (lane >> 4)) ^ (lane & 7);
      bfv[ni] = *(const short8*)(Bs + row * 128 + swz * 8);
    }
#pragma unroll
    for (int mi = 0; mi < 4; ++mi)
#pragma unroll
      for (int ni = 0; ni < 4; ++ni)
        acc[mi][ni] = __builtin_amdgcn_mfma_f32_16x16x32_bf16(af[mi], bfv[ni], acc[mi][ni], 0, 0, 0);
  }
  __syncthreads();  // all LDS reads done before Tb overwrite

  // epilogue: u = acc + hc*scoef + bg, relu -> Tb (bf16)
  float hcv[4], bgv[4];
#pragma unroll
  for (int ni = 0; ni < 4; ++ni) {
    int n = wn * 64 + ni * 16 + (lane & 15);
    hcv[ni] = hcS[n];
    bgv[ni] = bgS[n];
  }
#pragma unroll
  for (int mi = 0; mi < 4; ++mi) {
#pragma unroll
    for (int r = 0; r < 4; ++r) {
      int m = wm * 64 + mi * 16 + (lane >> 4) * 4 + r;
      int gr = bRow + m;
      float sc = (gr < N) ? scoef[gr] : 0.f;
#pragma unroll
      for (int ni = 0; ni < 4; ++ni) {
        float u = fmaxf(acc[mi][ni][r] + hcv[ni] * sc + bgv[ni], 0.f);
        Tb[m * 136 + wn * 64 + ni * 16 + (lane & 15)] = f2bf(u);
      }
    }
  }
  __syncthreads();

  // classifier + log_softmax: 2 threads per row
  int r2 = tid >> 1, qd = tid & 1;
  float part[10];
#pragma unroll
  for (int t = 0; t < 10; ++t) part[t] = 0.f;
  for (int jj = 0; jj < 64; ++jj) {
    int j = qd * 64 + jj;
    float a = bf2f(Tb[r2 * 136 + j]);
#pragma unroll
    for (int t = 0; t < 10; ++t) part[t] = fmaf(a, WcS[j * 10 + t], part[t]);
  }
#pragma unroll
  for (int t = 0; t < 10; ++t) part[t] += __shfl_xor(part[t], 1);
  int gr = bRow + r2;
  if (qd == 0 && gr < N) {
    float l[10], m = -1e30f;
#pragma unroll
    for (int t = 0; t < 10; ++t) {
      l[t] = part[t] + bcS[t];
      m = fmaxf(m, l[t]);
    }
    float se = 0.f;
#pragma unroll
    for (int t = 0; t < 10; ++t) se += expf(l[t] - m);
    float lse = m + logf(se);
#pragma unroll
    for (int t = 0; t < 10; ++t) out[(size_t)gr * 10 + t] = l[t] - lse;
  }
}

// ---------------------------------------------------------------------------
extern "C" void kernel_launch(void* const* d_in, const int* in_sizes, int n_in,
                              void* d_out, int out_size, void* d_ws, size_t ws_size,
                              hipStream_t stream) {
  const float* X = (const float*)d_in[0];
  const int* ei = (const int*)d_in[2];
  const float* gamma1 = (const float*)d_in[3];
  const float* beta1 = (const float*)d_in[4];
  const float* Wmlp = (const float*)d_in[5];
  const float* bmlp = (const float*)d_in[6];
  const float* gamma2 = (const float*)d_in[7];
  const float* beta2 = (const float*)d_in[8];
  const float* Wgcn = (const float*)d_in[9];
  const float* bgcn = (const float*)d_in[10];
  const float* Wcls = (const float*)d_in[11];
  const float* bcls = (const float*)d_in[12];
  float* out = (float*)d_out;

  const int N = in_sizes[0] / 512;
  const int E = in_sizes[2] / 2;
  const float invN = 1.0f / (float)N;

  char* ws = (char*)d_ws;
  float* s1 = (float*)(ws + 0);            // 512
  float* q1 = (float*)(ws + 2048);         // 512
  float* s2 = (float*)(ws + 4096);         // 128
  float* q2 = (float*)(ws + 4608);         // 128
  float* b1p = (float*)(ws + 5120);        // 128
  float* hconst = (float*)(ws + 5632);     // 128
  u16* W1bT = (u16*)(ws + 8192);           // 128*512 bf16 -> ends 139264
  u16* W2bT = (u16*)(ws + 139264);         // 128*128 bf16 -> ends 172032
  int* bsums = (int*)(ws + 172032);        // 256 -> 173056
  int* deg = (int*)(ws + 173056);          // N
  int* cursor = (int*)(ws + 373056);       // N
  int* offs = (int*)(ws + 573056);         // N
  float* dinv = (float*)(ws + 773056);     // N
  float* scoef = (float*)(ws + 973056);    // N
  int* col = (int*)(ws + 1173056);         // E -> 4373056
  u16* Yb = (u16*)(ws + 4373504);          // N*128 bf16 -> 17173504
  u16* Ab = (u16*)(ws + 17173504);         // N*128 bf16 -> 29973504
  u16* Xb = (u16*)(ws + 29973504);         // N*512 bf16 -> 81173504
  float* pS1 = (float*)(ws + 81173504);    // 2048*512 -> 85367808
  float* pQ1 = (float*)(ws + 85367808);    // 2048*512 -> 89562112
  float* pS2 = (float*)(ws + 89562112);    // 391*128 -> 89762304
  float* pQ2 = (float*)(ws + 89762304);    // 391*128 -> 89962496
  (void)ws_size; (void)n_in; (void)out_size;

  const int* esrc = ei;
  const int* edst = ei + E;
  int nb = (N + 255) / 256;
  int eb = (E + 255) / 256;
  int gb = (N + 127) / 128;  // 391

  // zero stats + b1p + hconst (contiguous 1536 floats at ws+0)
  k_zero<<<6, 256, 0, stream>>>(s1, 1536);
  k_zero<<<(2 * N + 255) / 256, 256, 0, stream>>>((float*)deg, 2 * N);

  k_bn1_statsX<<<2048, 256, 0, stream>>>(X, N, pS1, pQ1, Xb);
  k_red1<<<16, 256, 0, stream>>>(pS1, pQ1, s1, q1, 2048, 128);
  k_foldwT<<<256, 256, 0, stream>>>(s1, q1, gamma1, Wmlp, W1bT, invN, 9);
  k_foldb_par<<<16, 256, 0, stream>>>(s1, q1, gamma1, beta1, Wmlp, bmlp, b1p, invN, 32);
  k_gemm1<<<gb, 256, 0, stream>>>(Xb, W1bT, b1p, Yb, pS2, pQ2, N);
  k_red2<<<8, 256, 0, stream>>>(pS2, pQ2, s2, q2, gb, (gb + 7) / 8);

  k_deg<<<eb, 256, 0, stream>>>(edst, E, deg);
  k_scan1<<<nb, 256, 0, stream>>>(deg, N, offs, bsums, dinv);
  k_scan2<<<1, 256, 0, stream>>>(bsums, nb);
  k_scan3<<<nb, 256, 0, stream>>>(offs, bsums, N);
  k_scatter<<<eb, 256, 0, stream>>>(esrc, edst, E, offs, cursor, col);

  k_foldwT<<<64, 256, 0, stream>>>(s2, q2, gamma2, Wgcn, W2bT, invN, 7);
  k_foldb_par<<<8, 256, 0, stream>>>(s2, q2, gamma2, beta2, Wgcn, nullptr, hconst, invN, 16);

  k_gather<<<(N + 3) / 4, 256, 0, stream>>>(Yb, col, offs, deg, dinv, Ab, scoef, N);
  k_final<<<gb, 256, 0, stream>>>(Ab, W2bT, hconst, scoef, bgcn, Wcls, bcls, out, N);
}

// Round 7
// 237.674 us; speedup vs baseline: 1.6698x; 1.0502x over previous
//
#include <hip/hip_runtime.h>
#include <math.h>

#define EPS 1e-5f

typedef short short8 __attribute__((ext_vector_type(8)));
typedef float f32x4 __attribute__((ext_vector_type(4)));
typedef unsigned short u16;
typedef u16 u16x4 __attribute__((ext_vector_type(4)));

__device__ inline u16 f2bf(float f) {
  union { float f; unsigned u; } x; x.f = f;
  return (u16)((x.u + 0x7fffu + ((x.u >> 16) & 1u)) >> 16);
}
__device__ inline float bf2f(u16 h) {
  union { float f; unsigned u; } x; x.u = ((unsigned)h) << 16;
  return x.f;
}

__device__ inline void gload_lds16(const void* g, void* l) {
  __builtin_amdgcn_global_load_lds((const __attribute__((address_space(1))) void*)g,
                                   (__attribute__((address_space(3))) void*)l, 16, 0, 0);
}

// ---------- zero two buffers in one launch ----------
__global__ void k_zero2(float* __restrict__ a, int na, float* __restrict__ b, int nb) {
  int i = blockIdx.x * 256 + threadIdx.x;
  if (i < na) a[i] = 0.f;
  else if (i - na < nb) b[i - na] = 0.f;
}

// ---------- BN1 column stats over X [N,512] + bf16 cast of X ----------
// Grid-stride float4 stream; per-block partials (NO same-address global atomics).
__global__ __launch_bounds__(256)
void k_bn1_statsX(const float* __restrict__ X, int N, float* __restrict__ pS,
                  float* __restrict__ pQ, u16* __restrict__ Xb) {
  __shared__ float shs[1024], shq[1024];
  int tid = threadIdx.x;
  float sum[4] = {0.f, 0.f, 0.f, 0.f}, sq[4] = {0.f, 0.f, 0.f, 0.f};
  size_t total = (size_t)N * 128;
  size_t stride = (size_t)gridDim.x * 256;
  for (size_t i = (size_t)blockIdx.x * 256 + tid; i < total; i += stride) {
    float4 v = ((const float4*)X)[i];
    u16x4 h;
    h[0] = f2bf(v.x); h[1] = f2bf(v.y); h[2] = f2bf(v.z); h[3] = f2bf(v.w);
    ((u16x4*)Xb)[i] = h;
    sum[0] += v.x; sq[0] += v.x * v.x;
    sum[1] += v.y; sq[1] += v.y * v.y;
    sum[2] += v.z; sq[2] += v.z * v.z;
    sum[3] += v.w; sq[3] += v.w * v.w;
  }
#pragma unroll
  for (int i = 0; i < 4; ++i) { shs[tid * 4 + i] = sum[i]; shq[tid * 4 + i] = sq[i]; }
  __syncthreads();
  if (tid < 128) {
#pragma unroll
    for (int i = 0; i < 4; ++i) {
      float a = shs[tid * 4 + i] + shs[(tid + 128) * 4 + i];
      float b = shq[tid * 4 + i] + shq[(tid + 128) * 4 + i];
      pS[(size_t)blockIdx.x * 512 + tid * 4 + i] = a;
      pQ[(size_t)blockIdx.x * 512 + tid * 4 + i] = b;
    }
  }
}

// ---------- reduce stage-1 partials: s[col] = sum_p pS[p][col], 512 cols ----------
__global__ __launch_bounds__(256)
void k_red1(const float* __restrict__ pS, const float* __restrict__ pQ,
            float* __restrict__ s, float* __restrict__ q, int P, int per) {
  int t = threadIdx.x;
  int p0 = blockIdx.x * per;
  int p1 = p0 + per; if (p1 > P) p1 = P;
  float a0 = 0.f, a1 = 0.f, b0 = 0.f, b1 = 0.f;
  for (int p = p0; p < p1; ++p) {
    a0 += pS[(size_t)p * 512 + t];
    a1 += pS[(size_t)p * 512 + t + 256];
    b0 += pQ[(size_t)p * 512 + t];
    b1 += pQ[(size_t)p * 512 + t + 256];
  }
  atomicAdd(&s[t], a0); atomicAdd(&s[t + 256], a1);
  atomicAdd(&q[t], b0); atomicAdd(&q[t + 256], b1);
}

// ---------- reduce gemm1 partials: 128 cols ----------
__global__ __launch_bounds__(256)
void k_red2(const float* __restrict__ pS, const float* __restrict__ pQ,
            float* __restrict__ s, float* __restrict__ q, int NB, int per) {
  int t = threadIdx.x;
  int col = t & 127;
  const float* src = (t >= 128) ? pQ : pS;
  int p0 = blockIdx.x * per;
  int p1 = p0 + per; if (p1 > NB) p1 = NB;
  float a = 0.f;
  for (int p = p0; p < p1; ++p) a += src[(size_t)p * 128 + col];
  atomicAdd((t >= 128) ? &q[col] : &s[col], a);
}

// ---------- merged fold: blocks [0,wb) do WT[j][k]=a[k]*W[k][j]; blocks [wb,wb+fb)
// do split-K bias fold bp[j] += sum_k c[k]*W[k][j] (bp pre-zeroed) ----------
__global__ __launch_bounds__(256)
void k_fold(const float* __restrict__ s, const float* __restrict__ q,
            const float* __restrict__ gamma, const float* __restrict__ beta,
            const float* __restrict__ W, const float* __restrict__ b,
            u16* __restrict__ WT, float* __restrict__ bp,
            float invN, int lgK, int wb, int kPerBlock) {
  int K = 1 << lgK;
  if ((int)blockIdx.x < wb) {
    int idx = blockIdx.x * 256 + threadIdx.x;
    int k = idx & (K - 1);
    float mu = s[k] * invN;
    float var = fmaxf(q[k] * invN - mu * mu, 0.f);
    float a = gamma[k] * rsqrtf(var + EPS);
    WT[idx] = f2bf(a * W[(size_t)k * 128 + (idx >> lgK)]);
  } else {
    __shared__ float sh[256];
    int j = threadIdx.x & 127;
    int ksub = threadIdx.x >> 7;
    int k0 = (blockIdx.x - wb) * kPerBlock;
    float acc = 0.f;
    for (int k = k0 + ksub; k < k0 + kPerBlock; k += 2) {
      float mu = s[k] * invN;
      float var = fmaxf(q[k] * invN - mu * mu, 0.f);
      float a = gamma[k] * rsqrtf(var + EPS);
      float c = beta[k] - mu * a;
      acc = fmaf(c, W[(size_t)k * 128 + j], acc);
    }
    sh[threadIdx.x] = acc;
    __syncthreads();
    if (threadIdx.x < 128) {
      float v = sh[threadIdx.x] + sh[threadIdx.x + 128];
      if (blockIdx.x == (unsigned)wb) v += (b ? b[j] : 0.f);
      atomicAdd(&bp[j], v);
    }
  }
}

// ---------- GEMM1 (MFMA bf16): Yb = relu(Xb@W1p + bp) as bf16; partial col stats ----------
__global__ __launch_bounds__(256)
void k_gemm1(const u16* __restrict__ Xb, const u16* __restrict__ WT,
             const float* __restrict__ bp, u16* __restrict__ Yb,
             float* __restrict__ pS2, float* __restrict__ pQ2, int N) {
  __shared__ __align__(16) u16 As[128 * 64];
  __shared__ __align__(16) u16 Bs[128 * 64];
  __shared__ float csum[128], cq[128];
  int tid = threadIdx.x;
  if (tid < 128) { csum[tid] = 0.f; cq[tid] = 0.f; }
  int lane = tid & 63, wid = tid >> 6;
  int wm = wid & 1, wn = wid >> 1;
  int bRow = blockIdx.x * 128;

  f32x4 acc[4][4];
#pragma unroll
  for (int mi = 0; mi < 4; ++mi)
#pragma unroll
    for (int ni = 0; ni < 4; ++ni) acc[mi][ni] = {0.f, 0.f, 0.f, 0.f};

  for (int k0 = 0; k0 < 512; k0 += 64) {
    __syncthreads();
#pragma unroll
    for (int i = 0; i < 4; ++i) {
      int p = i * 256 + tid;
      int row = p >> 3, slot = p & 7, srs = slot ^ (row & 7);
      int gr = bRow + row; if (gr >= N) gr = N - 1;
      gload_lds16(Xb + (size_t)gr * 512 + (k0 + srs * 8), (char*)As + p * 16);
      gload_lds16(WT + (size_t)row * 512 + (k0 + srs * 8), (char*)Bs + p * 16);
    }
    __syncthreads();
#pragma unroll
    for (int ks = 0; ks < 2; ++ks) {
      short8 af[4], bfv[4];
#pragma unroll
      for (int mi = 0; mi < 4; ++mi) {
        int row = wm * 64 + mi * 16 + (lane & 15);
        int swz = (ks * 4 + (lane >> 4)) ^ (lane & 7);
        af[mi] = *(const short8*)(As + row * 64 + swz * 8);
      }
#pragma unroll
      for (int ni = 0; ni < 4; ++ni) {
        int row = wn * 64 + ni * 16 + (lane & 15);
        int swz = (ks * 4 + (lane >> 4)) ^ (lane & 7);
        bfv[ni] = *(const short8*)(Bs + row * 64 + swz * 8);
      }
#pragma unroll
      for (int mi = 0; mi < 4; ++mi)
#pragma unroll
        for (int ni = 0; ni < 4; ++ni)
          acc[mi][ni] = __builtin_amdgcn_mfma_f32_16x16x32_bf16(af[mi], bfv[ni], acc[mi][ni], 0, 0, 0);
    }
  }

  float bias[4];
#pragma unroll
  for (int ni = 0; ni < 4; ++ni) bias[ni] = bp[wn * 64 + ni * 16 + (lane & 15)];
  float colp[4] = {0, 0, 0, 0}, colq[4] = {0, 0, 0, 0};
#pragma unroll
  for (int mi = 0; mi < 4; ++mi) {
#pragma unroll
    for (int r = 0; r < 4; ++r) {
      int gr = bRow + wm * 64 + mi * 16 + (lane >> 4) * 4 + r;
      if (gr < N) {
#pragma unroll
        for (int ni = 0; ni < 4; ++ni) {
          float u = fmaxf(acc[mi][ni][r] + bias[ni], 0.f);
          colp[ni] += u;
          colq[ni] += u * u;
          Yb[(size_t)gr * 128 + wn * 64 + ni * 16 + (lane & 15)] = f2bf(u);
        }
      }
    }
  }
#pragma unroll
  for (int ni = 0; ni < 4; ++ni) {
    float a = colp[ni], b = colq[ni];
    a += __shfl_xor(a, 16); a += __shfl_xor(a, 32);
    b += __shfl_xor(b, 16); b += __shfl_xor(b, 32);
    if (lane < 16) {
      atomicAdd(&csum[wn * 64 + ni * 16 + lane], a);
      atomicAdd(&cq[wn * 64 + ni * 16 + lane], b);
    }
  }
  __syncthreads();
  if (tid < 128) {
    pS2[(size_t)blockIdx.x * 128 + tid] = csum[tid];
    pQ2[(size_t)blockIdx.x * 128 + tid] = cq[tid];
  }
}

// ---------- degree count ----------
__global__ void k_deg(const int* __restrict__ dst, int E, int* __restrict__ deg) {
  int e = blockIdx.x * 256 + threadIdx.x;
  if (e < E) atomicAdd(&deg[dst[e]], 1);
}

// ---------- scans (block-local exclusive; bsums fixed up at use-sites) ----------
__global__ __launch_bounds__(256)
void k_scan1(const int* __restrict__ deg, int N, int* __restrict__ offs,
             int* __restrict__ bsums, float* __restrict__ dinv) {
  __shared__ int sh[256];
  int t = threadIdx.x;
  int i = blockIdx.x * 256 + t;
  int c = (i < N) ? deg[i] : 0;
  if (i < N) dinv[i] = rsqrtf((float)(c + 1));
  int val = c;
  sh[t] = val;
  __syncthreads();
  for (int off = 1; off < 256; off <<= 1) {
    int add = (t >= off) ? sh[t - off] : 0;
    __syncthreads();
    val += add;
    sh[t] = val;
    __syncthreads();
  }
  if (i < N) offs[i] = val - c;
  if (t == 255) bsums[blockIdx.x] = val;
}

__global__ __launch_bounds__(256)
void k_scan2(int* __restrict__ bsums, int nb) {
  __shared__ int sh[256];
  int t = threadIdx.x;
  int v = (t < nb) ? bsums[t] : 0;
  int val = v;
  sh[t] = val;
  __syncthreads();
  for (int off = 1; off < 256; off <<= 1) {
    int add = (t >= off) ? sh[t - off] : 0;
    __syncthreads();
    val += add;
    sh[t] = val;
    __syncthreads();
  }
  if (t < nb) bsums[t] = val - v;
}

// ---------- scatter src ids into CSR buckets (offs + bsums fused) ----------
__global__ void k_scatter(const int* __restrict__ src, const int* __restrict__ dst, int E,
                          const int* __restrict__ offs, const int* __restrict__ bsums,
                          int* __restrict__ cursor, int* __restrict__ col) {
  int e = blockIdx.x * 256 + threadIdx.x;
  if (e < E) {
    int d = dst[e];
    int p = atomicAdd(&cursor[d], 1);
    col[offs[d] + bsums[d >> 8] + p] = src[e];
  }
}

// ---------- gather (bf16 Y -> bf16 A): one wave per dst node, 8-way unrolled ----------
__global__ __launch_bounds__(256)
void k_gather(const u16* __restrict__ Yb, const int* __restrict__ col,
              const int* __restrict__ offs, const int* __restrict__ bsums,
              const int* __restrict__ deg, const float* __restrict__ dinv,
              u16* __restrict__ Ab, float* __restrict__ scoef, int N) {
  int wid = threadIdx.x >> 6;
  int lane = threadIdx.x & 63;
  int d = blockIdx.x * 4 + wid;
  if (d >= N) return;
  int p = offs[d] + bsums[d >> 8];
  int c = deg[d];
  float dd = dinv[d];
  float ax, ay;
  {
    unsigned v = ((const unsigned*)(Yb + (size_t)d * 128))[lane];
    ax = dd * bf2f((u16)v);
    ay = dd * bf2f((u16)(v >> 16));
  }
  float sw = 0.f;
  for (int base = 0; base < c; base += 64) {
    int rem = c - base;
    if (rem > 64) rem = 64;
    int sidx = 0;
    float w = 0.f;
    if (lane < rem) {
      sidx = col[p + base + lane];
      w = dinv[sidx];
    }
    sw += w;
    int j = 0;
    for (; j + 7 < rem; j += 8) {
      int ss[8]; float ww[8]; unsigned vv[8];
#pragma unroll
      for (int u = 0; u < 8; ++u) { ss[u] = __shfl(sidx, j + u); ww[u] = __shfl(w, j + u); }
#pragma unroll
      for (int u = 0; u < 8; ++u) vv[u] = ((const unsigned*)(Yb + (size_t)ss[u] * 128))[lane];
#pragma unroll
      for (int u = 0; u < 8; ++u) {
        ax = fmaf(ww[u], bf2f((u16)vv[u]), ax);
        ay = fmaf(ww[u], bf2f((u16)(vv[u] >> 16)), ay);
      }
    }
    for (; j + 3 < rem; j += 4) {
      int s0 = __shfl(sidx, j), s1 = __shfl(sidx, j + 1);
      int s2 = __shfl(sidx, j + 2), s3 = __shfl(sidx, j + 3);
      float w0 = __shfl(w, j), w1 = __shfl(w, j + 1);
      float w2 = __shfl(w, j + 2), w3 = __shfl(w, j + 3);
      unsigned v0 = ((const unsigned*)(Yb + (size_t)s0 * 128))[lane];
      unsigned v1 = ((const unsigned*)(Yb + (size_t)s1 * 128))[lane];
      unsigned v2 = ((const unsigned*)(Yb + (size_t)s2 * 128))[lane];
      unsigned v3 = ((const unsigned*)(Yb + (size_t)s3 * 128))[lane];
      ax = fmaf(w0, bf2f((u16)v0), ax); ay = fmaf(w0, bf2f((u16)(v0 >> 16)), ay);
      ax = fmaf(w1, bf2f((u16)v1), ax); ay = fmaf(w1, bf2f((u16)(v1 >> 16)), ay);
      ax = fmaf(w2, bf2f((u16)v2), ax); ay = fmaf(w2, bf2f((u16)(v2 >> 16)), ay);
      ax = fmaf(w3, bf2f((u16)v3), ax); ay = fmaf(w3, bf2f((u16)(v3 >> 16)), ay);
    }
    for (; j < rem; ++j) {
      int sj = __shfl(sidx, j);
      float wj = __shfl(w, j);
      unsigned v = ((const unsigned*)(Yb + (size_t)sj * 128))[lane];
      ax = fmaf(wj, bf2f((u16)v), ax);
      ay = fmaf(wj, bf2f((u16)(v >> 16)), ay);
    }
  }
#pragma unroll
  for (int off = 32; off; off >>= 1) sw += __shfl_xor(sw, off);
  unsigned o = (unsigned)f2bf(ax * dd) | ((unsigned)f2bf(ay * dd) << 16);
  ((unsigned*)(Ab + (size_t)d * 128))[lane] = o;
  if (lane == 0) scoef[d] = dd * (sw + dd);
}

// ---------- final (MFMA bf16, BK=128 single pass) ----------
__global__ __launch_bounds__(256)
void k_final(const u16* __restrict__ Ab, const u16* __restrict__ W2T,
             const float* __restrict__ hc, const float* __restrict__ scoef,
             const float* __restrict__ bg, const float* __restrict__ Wcls,
             const float* __restrict__ bcls, float* __restrict__ out, int N) {
  __shared__ __align__(16) char smem[65536];
  __shared__ float WcS[1280];
  __shared__ float hcS[128], bgS[128], bcS[10];
  u16* As = (u16*)smem;
  u16* Bs = (u16*)(smem + 32768);
  u16* Tb = (u16*)smem;  // reused after compute: [128][136] bf16
  int tid = threadIdx.x;
  for (int i = tid; i < 1280; i += 256) WcS[i] = Wcls[i];
  if (tid < 128) { hcS[tid] = hc[tid]; bgS[tid] = bg[tid]; }
  if (tid < 10) bcS[tid] = bcls[tid];
  int lane = tid & 63, wid = tid >> 6;
  int wm = wid & 1, wn = wid >> 1;
  int bRow = blockIdx.x * 128;

#pragma unroll
  for (int i = 0; i < 8; ++i) {
    int p = i * 256 + tid;
    int row = p >> 4, slot = p & 15, srs = slot ^ (row & 7);
    int gr = bRow + row; if (gr >= N) gr = N - 1;
    gload_lds16(Ab + (size_t)gr * 128 + srs * 8, (char*)As + p * 16);
    gload_lds16(W2T + (size_t)row * 128 + srs * 8, (char*)Bs + p * 16);
  }
  f32x4 acc[4][4];
#pragma unroll
  for (int mi = 0; mi < 4; ++mi)
#pragma unroll
    for (int ni = 0; ni < 4; ++ni) acc[mi][ni] = {0.f, 0.f, 0.f, 0.f};
  __syncthreads();
#pragma unroll
  for (int ks = 0; ks < 4; ++ks) {
    short8 af[4], bfv[4];
#pragma unroll
    for (int mi = 0; mi < 4; ++mi) {
      int row = wm * 64 + mi * 16 + (lane & 15);
      int swz = (ks * 4 + (lane >> 4)) ^ (lane & 7);
      af[mi] = *(const short8*)(As + row * 128 + swz * 8);
    }
#pragma unroll
    for (int ni = 0; ni < 4; ++ni) {
      int row = wn * 64 + ni * 16 + (lane & 15);
      int swz = (ks * 4 + (lane >> 4)) ^ (lane & 7);
      bfv[ni] = *(const short8*)(Bs + row * 128 + swz * 8);
    }
#pragma unroll
    for (int mi = 0; mi < 4; ++mi)
#pragma unroll
      for (int ni = 0; ni < 4; ++ni)
        acc[mi][ni] = __builtin_amdgcn_mfma_f32_16x16x32_bf16(af[mi], bfv[ni], acc[mi][ni], 0, 0, 0);
  }
  __syncthreads();

  float hcv[4], bgv[4];
#pragma unroll
  for (int ni = 0; ni < 4; ++ni) {
    int n = wn * 64 + ni * 16 + (lane & 15);
    hcv[ni] = hcS[n];
    bgv[ni] = bgS[n];
  }
#pragma unroll
  for (int mi = 0; mi < 4; ++mi) {
#pragma unroll
    for (int r = 0; r < 4; ++r) {
      int m = wm * 64 + mi * 16 + (lane >> 4) * 4 + r;
      int gr = bRow + m;
      float sc = (gr < N) ? scoef[gr] : 0.f;
#pragma unroll
      for (int ni = 0; ni < 4; ++ni) {
        float u = fmaxf(acc[mi][ni][r] + hcv[ni] * sc + bgv[ni], 0.f);
        Tb[m * 136 + wn * 64 + ni * 16 + (lane & 15)] = f2bf(u);
      }
    }
  }
  __syncthreads();

  int r2 = tid >> 1, qd = tid & 1;
  float part[10];
#pragma unroll
  for (int t = 0; t < 10; ++t) part[t] = 0.f;
  for (int jj = 0; jj < 64; ++jj) {
    int j = qd * 64 + jj;
    float a = bf2f(Tb[r2 * 136 + j]);
#pragma unroll
    for (int t = 0; t < 10; ++t) part[t] = fmaf(a, WcS[j * 10 + t], part[t]);
  }
#pragma unroll
  for (int t = 0; t < 10; ++t) part[t] += __shfl_xor(part[t], 1);
  int gr = bRow + r2;
  if (qd == 0 && gr < N) {
    float l[10], m = -1e30f;
#pragma unroll
    for (int t = 0; t < 10; ++t) {
      l[t] = part[t] + bcS[t];
      m = fmaxf(m, l[t]);
    }
    float se = 0.f;
#pragma unroll
    for (int t = 0; t < 10; ++t) se += expf(l[t] - m);
    float lse = m + logf(se);
#pragma unroll
    for (int t = 0; t < 10; ++t) out[(size_t)gr * 10 + t] = l[t] - lse;
  }
}

// ---------------------------------------------------------------------------
extern "C" void kernel_launch(void* const* d_in, const int* in_sizes, int n_in,
                              void* d_out, int out_size, void* d_ws, size_t ws_size,
                              hipStream_t stream) {
  const float* X = (const float*)d_in[0];
  const int* ei = (const int*)d_in[2];
  const float* gamma1 = (const float*)d_in[3];
  const float* beta1 = (const float*)d_in[4];
  const float* Wmlp = (const float*)d_in[5];
  const float* bmlp = (const float*)d_in[6];
  const float* gamma2 = (const float*)d_in[7];
  const float* beta2 = (const float*)d_in[8];
  const float* Wgcn = (const float*)d_in[9];
  const float* bgcn = (const float*)d_in[10];
  const float* Wcls = (const float*)d_in[11];
  const float* bcls = (const float*)d_in[12];
  float* out = (float*)d_out;

  const int N = in_sizes[0] / 512;
  const int E = in_sizes[2] / 2;
  const float invN = 1.0f / (float)N;

  char* ws = (char*)d_ws;
  float* s1 = (float*)(ws + 0);            // 512
  float* q1 = (float*)(ws + 2048);         // 512
  float* s2 = (float*)(ws + 4096);         // 128
  float* q2 = (float*)(ws + 4608);         // 128
  float* b1p = (float*)(ws + 5120);        // 128
  float* hconst = (float*)(ws + 5632);     // 128
  u16* W1bT = (u16*)(ws + 8192);           // 128*512 bf16
  u16* W2bT = (u16*)(ws + 139264);         // 128*128 bf16
  int* bsums = (int*)(ws + 172032);        // 256
  int* deg = (int*)(ws + 173056);          // N
  int* cursor = (int*)(ws + 373056);       // N
  int* offs = (int*)(ws + 573056);         // N
  float* dinv = (float*)(ws + 773056);     // N
  float* scoef = (float*)(ws + 973056);    // N
  int* col = (int*)(ws + 1173056);         // E
  u16* Yb = (u16*)(ws + 4373504);          // N*128 bf16
  u16* Ab = (u16*)(ws + 17173504);         // N*128 bf16
  u16* Xb = (u16*)(ws + 29973504);         // N*512 bf16
  float* pS1 = (float*)(ws + 81173504);    // 2048*512
  float* pQ1 = (float*)(ws + 85367808);    // 2048*512
  float* pS2 = (float*)(ws + 89562112);    // 391*128
  float* pQ2 = (float*)(ws + 89762304);    // 391*128
  (void)ws_size; (void)n_in; (void)out_size;

  const int* esrc = ei;
  const int* edst = ei + E;
  int nb = (N + 255) / 256;
  int eb = (E + 255) / 256;
  int gb = (N + 127) / 128;  // 391

  // zero stats+b1p+hconst (1536 floats) and deg+cursor (2N ints) in one launch
  k_zero2<<<(1536 + 2 * N + 255) / 256, 256, 0, stream>>>(s1, 1536, (float*)deg, 2 * N);

  k_bn1_statsX<<<2048, 256, 0, stream>>>(X, N, pS1, pQ1, Xb);
  k_red1<<<16, 256, 0, stream>>>(pS1, pQ1, s1, q1, 2048, 128);
  k_fold<<<272, 256, 0, stream>>>(s1, q1, gamma1, beta1, Wmlp, bmlp, W1bT, b1p, invN, 9, 256, 32);
  k_gemm1<<<gb, 256, 0, stream>>>(Xb, W1bT, b1p, Yb, pS2, pQ2, N);
  k_red2<<<8, 256, 0, stream>>>(pS2, pQ2, s2, q2, gb, (gb + 7) / 8);

  k_deg<<<eb, 256, 0, stream>>>(edst, E, deg);
  k_scan1<<<nb, 256, 0, stream>>>(deg, N, offs, bsums, dinv);
  k_scan2<<<1, 256, 0, stream>>>(bsums, nb);
  k_scatter<<<eb, 256, 0, stream>>>(esrc, edst, E, offs, bsums, cursor, col);

  k_fold<<<72, 256, 0, stream>>>(s2, q2, gamma2, beta2, Wgcn, nullptr, W2bT, hconst, invN, 7, 64, 16);

  k_gather<<<(N + 3) / 4, 256, 0, stream>>>(Yb, col, offs, bsums, deg, dinv, Ab, scoef, N);
  k_final<<<gb, 256, 0, stream>>>(Ab, W2bT, hconst, scoef, bgcn, Wcls, bcls, out, N);
}